// Round 1
// baseline (115.433 us; speedup 1.0000x reference)
//
#include <hip/hip_runtime.h>

// GSKAN layer: out[b,q] = sum_p prelu(x[b,p] + eps[q]) * Lam[p,q]
// prelu(s) = c1*s + c2*|s|,  c1 = (1+a)/2, c2 = (1-a)/2  (|s| is a free VOP3 input modifier)
//
// Main kernel: 256 threads, output tile 64(b) x 64(q), 4x4 per thread.
// p dimension split across blockIdx.z into partial sums (deterministic combine kernel after).

#define PCHUNK 64

__global__ __launch_bounds__(256) void gskan_partial_kernel(
    const float* __restrict__ X,     // [B][n_in]
    const float* __restrict__ Lam,   // [n_in][n_out]
    const float* __restrict__ Eps,   // [n_out]
    const float* __restrict__ Aw,    // [1]
    float* __restrict__ Part,        // [nsplit][B][n_out]
    int B, int n_in, int n_out, int p_per_split)
{
    __shared__ float xs[64][PCHUNK + 4];  // [b][p], +4 pad keeps 16B align, breaks bank stride
    __shared__ float ls[PCHUNK][64];      // [p][q]

    const int tid = threadIdx.x;
    const int qg  = tid & 15;   // 16 q-groups of 4
    const int bl  = tid >> 4;   // 16 b-groups of 4

    const int q0 = blockIdx.x * 64;
    const int b0 = blockIdx.y * 64;
    const int p_begin = blockIdx.z * p_per_split;
    int p_end = p_begin + p_per_split;
    if (p_end > n_in) p_end = n_in;

    const float a  = Aw[0];
    const float c1 = 0.5f * (1.0f + a);
    const float c2 = 0.5f * (1.0f - a);

    const int q = q0 + qg * 4;
    const float4 epsv = *reinterpret_cast<const float4*>(Eps + q);
    const float ee[4] = {epsv.x, epsv.y, epsv.z, epsv.w};

    float acc1[4][4] = {};
    float acc2[4][4] = {};

    for (int pc = p_begin; pc < p_end; pc += PCHUNK) {
        // stage X tile: 64 rows x 64 p = 4096 floats, 4 float4 per thread, coalesced
        #pragma unroll
        for (int r = 0; r < 4; ++r) {
            int slot = r * 256 + tid;
            int row  = slot >> 4;
            int c4   = slot & 15;
            float4 v = *reinterpret_cast<const float4*>(
                X + (size_t)(b0 + row) * n_in + pc + c4 * 4);
            *reinterpret_cast<float4*>(&xs[row][c4 * 4]) = v;
        }
        // stage Lam tile: 64 p x 64 q
        #pragma unroll
        for (int r = 0; r < 4; ++r) {
            int slot = r * 256 + tid;
            int row  = slot >> 4;
            int c4   = slot & 15;
            float4 v = *reinterpret_cast<const float4*>(
                Lam + (size_t)(pc + row) * n_out + q0 + c4 * 4);
            *reinterpret_cast<float4*>(&ls[row][c4 * 4]) = v;
        }
        __syncthreads();

        for (int p = 0; p < PCHUNK; p += 4) {
            float4 xv[4];
            #pragma unroll
            for (int i = 0; i < 4; ++i)
                xv[i] = *reinterpret_cast<const float4*>(&xs[bl * 4 + i][p]);

            #pragma unroll
            for (int pp = 0; pp < 4; ++pp) {
                float4 lv = *reinterpret_cast<const float4*>(&ls[p + pp][qg * 4]);
                const float le[4] = {lv.x, lv.y, lv.z, lv.w};
                #pragma unroll
                for (int i = 0; i < 4; ++i) {
                    const float xe = (pp == 0) ? xv[i].x :
                                     (pp == 1) ? xv[i].y :
                                     (pp == 2) ? xv[i].z : xv[i].w;
                    #pragma unroll
                    for (int j = 0; j < 4; ++j) {
                        const float s = xe + ee[j];
                        acc1[i][j] = fmaf(s,        le[j], acc1[i][j]);
                        acc2[i][j] = fmaf(fabsf(s), le[j], acc2[i][j]);  // |s| = free modifier
                    }
                }
            }
        }
        __syncthreads();  // WAR: next chunk overwrites LDS
    }

    float* P = Part + (size_t)blockIdx.z * B * n_out;
    #pragma unroll
    for (int i = 0; i < 4; ++i) {
        const int b = b0 + bl * 4 + i;
        float4 o;
        o.x = c1 * acc1[i][0] + c2 * acc2[i][0];
        o.y = c1 * acc1[i][1] + c2 * acc2[i][1];
        o.z = c1 * acc1[i][2] + c2 * acc2[i][2];
        o.w = c1 * acc1[i][3] + c2 * acc2[i][3];
        *reinterpret_cast<float4*>(P + (size_t)b * n_out + q) = o;
    }
}

__global__ __launch_bounds__(256) void gskan_combine_kernel(
    const float* __restrict__ Part, float* __restrict__ Y, int n, int nsplit)
{
    int i = (blockIdx.x * 256 + threadIdx.x) * 4;
    if (i >= n) return;
    float4 acc = *reinterpret_cast<const float4*>(Part + i);
    for (int s = 1; s < nsplit; ++s) {
        float4 v = *reinterpret_cast<const float4*>(Part + (size_t)s * n + i);
        acc.x += v.x; acc.y += v.y; acc.z += v.z; acc.w += v.w;
    }
    *reinterpret_cast<float4*>(Y + i) = acc;
}

extern "C" void kernel_launch(void* const* d_in, const int* in_sizes, int n_in_args,
                              void* d_out, int out_size, void* d_ws, size_t ws_size,
                              hipStream_t stream)
{
    (void)n_in_args; (void)out_size;

    const float* x = (const float*)d_in[0];

    struct LayerP { const float *Lam, *Eps, *Aw; int n_in, n_out; };
    LayerP layers[4];
    for (int i = 0; i < 4; ++i) {
        layers[i].Lam   = (const float*)d_in[1 + 3 * i];
        layers[i].Eps   = (const float*)d_in[2 + 3 * i];
        layers[i].Aw    = (const float*)d_in[3 + 3 * i];
        layers[i].n_out = in_sizes[2 + 3 * i];
        layers[i].n_in  = in_sizes[1 + 3 * i] / layers[i].n_out;
    }
    const int B = in_sizes[0] / layers[0].n_in;

    // ws layout: [Part: 8MB][yA: 2MB][yB: 2MB]  (12MB needed for full p-split)
    char* ws = (char*)d_ws;
    float* Part = (float*)ws;
    float* yA   = (float*)(ws + (size_t)(8u << 20));
    float* yB   = (float*)(ws + (size_t)(10u << 20));
    const bool have_ws = ws_size >= (size_t)(12u << 20);

    const float* cur = x;
    for (int i = 0; i < 4; ++i) {
        const LayerP& ly = layers[i];
        const int nq = ly.n_out / 64;
        const int nb = B / 64;

        int nsplit = 1;
        if (have_ws) {
            nsplit = 512 / (nq * nb);                 // target ~512 blocks (2/CU, 8 waves/CU)
            if (nsplit < 1) nsplit = 1;
            int max_split = ly.n_in / PCHUNK;          // p_per_split must be >= PCHUNK
            if (nsplit > max_split) nsplit = max_split;
        }
        int p_per = ((ly.n_in + nsplit * PCHUNK - 1) / (nsplit * PCHUNK)) * PCHUNK;
        nsplit = (ly.n_in + p_per - 1) / p_per;

        float* Y = (i == 3) ? (float*)d_out : ((i % 2 == 0) ? yA : yB);
        float* dst = (nsplit == 1) ? Y : Part;

        dim3 grid(nq, nb, nsplit), block(256);
        hipLaunchKernelGGL(gskan_partial_kernel, grid, block, 0, stream,
                           cur, ly.Lam, ly.Eps, ly.Aw, dst,
                           B, ly.n_in, ly.n_out, p_per);

        if (nsplit > 1) {
            const int n = B * ly.n_out;
            dim3 cg((n / 4 + 255) / 256), cb(256);
            hipLaunchKernelGGL(gskan_combine_kernel, cg, cb, 0, stream, Part, Y, n, nsplit);
        }
        cur = Y;
    }
}